// Round 18
// baseline (338.535 us; speedup 1.0000x reference)
//
#include <hip/hip_runtime.h>
#include <hip/hip_bf16.h>

// Problem constants (fixed by reference)
#define BB  4
#define CC  64      // input channels
#define NN  4096    // W*H
#define CF  32      // f/g channels (CH/2)
#define CHN 64      // h channels

#define LOG2E 1.4426950408889634f

typedef __attribute__((ext_vector_type(8)))  __bf16 bf16x8;
typedef __attribute__((ext_vector_type(4)))  __bf16 bf16x4;
typedef __attribute__((ext_vector_type(4)))  float  floatx4;
typedef __attribute__((ext_vector_type(16))) float  floatx16;
typedef __attribute__((ext_vector_type(2)))  unsigned int uintx2;
typedef __attribute__((ext_vector_type(4)))  unsigned int uintx4;

__device__ __forceinline__ float scrub(float v) {
    return fminf(fmaxf(v, -1e30f), 1e30f);
}

// v_cvt_pk_bf16_f32 (r6-verified); v_exp_f32 = 2^x (r10-verified).
__device__ __forceinline__ unsigned cvt_pk_bf16(float lo, float hi) {
    unsigned r;
    asm("v_cvt_pk_bf16_f32 %0, %1, %2" : "=v"(r) : "v"(lo), "v"(hi));
    return r;
}
__device__ __forceinline__ float exp2_f32(float x) {
    float r;
    asm("v_exp_f32 %0, %1" : "=v"(r) : "v"(x));
    return r;
}

// Pairwise merge counters (r16-validated pattern: atomic total order picks
// exactly one "second" arrival per pair per launch; parity is launch-
// invariant since every launch adds exactly 2 per pair; no spinning).
__device__ unsigned pair_cnt[256];

// ---------------------------------------------------------------------------
// SWIZZLED WORKSPACE LAYOUTS (r11-verified, the -7.7us win). Every attn load
// instruction = one contiguous 1KB panel (lane sub-offset (l31*2+hi)*16B).
//   fT/gT (n,c): (n>>5)*1024 + (c>>4)*512 + (n&31)*16 + ((c>>3)&1)*8 + (c&7)
//   hvb  (ch,n): (n>>6)*4096 + (ch>>5)*2048 + ((n>>4)&3)*512
//                + (ch&31)*16 + ((n>>3)&1)*8 + (n&7)
// ---------------------------------------------------------------------------

// ---------------------------------------------------------------------------
// Kernel 1: 1x1 convs as MFMA GEMM (r11 verbatim).
// ---------------------------------------------------------------------------
__global__ __launch_bounds__(256) void prep_kernel(
    const float* __restrict__ x, const float* __restrict__ y,
    const float* __restrict__ Wf, const float* __restrict__ bfp,
    const float* __restrict__ Wg, const float* __restrict__ bgp,
    const float* __restrict__ Wh, const float* __restrict__ bhp,
    __bf16* __restrict__ fT, __bf16* __restrict__ gT, __bf16* __restrict__ hvb)
{
    __shared__ __align__(16) __bf16 wbf[128][72];
    __shared__ float sbias[128];

    const int t  = threadIdx.x;
    const int w  = t >> 6;               // 0..3
    const int l  = t & 63;
    const int lo = l & 15;
    const int q  = l >> 4;

    const int b   = blockIdx.x >> 7;
    const int nb  = blockIdx.x & 127;
    const int nn  = nb * 32 + (w & 1) * 16 + lo;   // 32 nn per block
    const int ctbase = (w < 2) ? 0 : 4;            // ct-half per wave pair

    for (int i = t; i < 128 * CC; i += 256) {
        int row = i >> 6, c = i & 63;
        float wv;
        if (row < 32)      wv = Wf[(size_t)row * CC + c];
        else if (row < 64) wv = Wg[(size_t)(row - 32) * CC + c];
        else               wv = Wh[(size_t)(row - 64) * CC + c];
        wbf[row][c] = (__bf16)wv;
    }
    if (t < 128) {
        if (t < 32)      sbias[t] = bfp[t];
        else if (t < 64) sbias[t] = bgp[t - 32];
        else             sbias[t] = bhp[t - 64];
    }
    __syncthreads();

    const float* xb = x + (size_t)b * CC * NN;
    const float* yb = y + (size_t)b * CC * NN;
    bf16x8 bx[2], by[2];
    #pragma unroll
    for (int kh = 0; kh < 2; kh++)
        #pragma unroll
        for (int j = 0; j < 8; j++) {
            int c = kh * 32 + q * 8 + j;
            by[kh][j] = (__bf16)yb[(size_t)c * NN + nn];
        }
    if (ctbase == 0) {      // bx only needed for ct 0,1
        #pragma unroll
        for (int kh = 0; kh < 2; kh++)
            #pragma unroll
            for (int j = 0; j < 8; j++) {
                int c = kh * 32 + q * 8 + j;
                bx[kh][j] = (__bf16)xb[(size_t)c * NN + nn];
            }
    }

    const floatx4 zero4 = {0.f, 0.f, 0.f, 0.f};
    #pragma unroll
    for (int cti = 0; cti < 4; cti++) {
        const int ct = ctbase + cti;
        const bf16x8* src = (ct < 2) ? bx : by;
        floatx4 acc = zero4;
        #pragma unroll
        for (int kh = 0; kh < 2; kh++) {
            const bf16x8 a = *(const bf16x8*)&wbf[ct*16 + lo][kh*32 + q*8];
            acc = __builtin_amdgcn_mfma_f32_16x16x32_bf16(a, src[kh], acc, 0, 0, 0);
        }
        if (ct < 4) {
            const float sc = (ct < 2) ? 1.0f : LOG2E;   // exp2-fold on g
            bf16x4 pk;
            #pragma unroll
            for (int r = 0; r < 4; r++)
                pk[r] = (__bf16)((acc[r] + sbias[ct*16 + q*4 + r]) * sc);
            __bf16* dstbase = (ct < 2) ? fT : gT;
            const int c0 = (ct & 1) * 16 + q * 4;
            const int off = (nn >> 5)*1024 + (c0 >> 4)*512 + (nn & 31)*16
                          + ((c0 >> 3) & 1)*8 + (c0 & 7);
            *(bf16x4*)&dstbase[(size_t)b * NN * CF + off] = pk;
        } else {
            #pragma unroll
            for (int r = 0; r < 4; r++) {
                int ch = (ct - 4) * 16 + q*4 + r;
                const int off = (nn >> 6)*4096 + (ch >> 5)*2048
                              + ((nn >> 4) & 3)*512 + (ch & 31)*16
                              + ((nn >> 3) & 1)*8 + (nn & 7);
                hvb[(size_t)b * CHN * NN + off] =
                    (__bf16)(acc[r] + sbias[64 + ch]);
            }
        }
    }
}

// ---------------------------------------------------------------------------
// Kernel 2: fused flash attention. r18 = THE CLEAN 4-waves/SIMD experiment:
// r11's exact loop body (2 m-subtiles, ~120 VGPR per r10 measurement, fits
// the 128 budget of __launch_bounds__(512,4)), grid 512 = 2 blocks/CU.
// Block = (b, 64-row mg, n-HALF): per-CU traffic, load-instruction count,
// MFMA and exp2 totals EXACTLY r11's — only waves/SIMD changes 2->4.
// Every prior occupancy attempt was confounded (r1 fences, r12/r16 spill,
// r13 duplication, r15 no-unroll+imbalance); r13's quantitative reading
// (2x instrs at 4w/SIMD -> only +18%) predicts this wins.
// LDS 70,660 B (two-pass merge through osum[8][32][67]) -> 2 blocks/CU.
// Cross-block n-half merge: r16-validated pairwise ws machinery (partials
// to pbuf, fence, atomic parity; first arrival exits, second merges +
// runs the fused epilogue). No spinning, no co-residency requirement.
// Spill tripwire: VGPR_Count=128 + inflated WRITE_SIZE => revert to r11.
// ---------------------------------------------------------------------------
__global__ __launch_bounds__(512, 4) void attn_kernel(
    const __bf16* __restrict__ fT, const __bf16* __restrict__ gT,
    const __bf16* __restrict__ hvb, float* __restrict__ pbuf,
    const float* __restrict__ x, const float* __restrict__ gamma_p,
    float* __restrict__ out)
{
    __shared__ float osum[8][32][67];   // 68,608 B
    __shared__ float lsum[512];         //   2,048 B  [slot*64 + mt*32 + row]
    __shared__ int   sflag;

    const int t   = threadIdx.x;
    const int w   = t >> 6;               // wave = n-parity (0..7)
    const int l   = t & 63;
    const int l31 = l & 31;
    const int hi  = l >> 5;

    // decode: xcd = slot&7 -> (b = xcd>>1, half = xcd&1). All blocks on an
    // XCD read one n-half of one batch -> ~0.7 MB L2 set. mg = slot>>3.
    const int slot = blockIdx.x;          // 0..511
    const int xcd  = slot & 7;
    const int b    = xcd >> 1;
    const int half = xcd & 1;             // n-half (chunks 0-31 / 32-63)
    const int mg   = slot >> 3;           // 0..63
    const int m0   = mg * 64;
    const int pair = mg * 4 + b;          // 0..255

    const __bf16* fb = fT  + (size_t)b * NN * CF;
    const __bf16* gb = gT  + (size_t)b * NN * CF;
    const __bf16* hb = hvb + (size_t)b * CHN * NN;

    const int lane16 = (l31 * 2 + hi) * 8;   // elem sub-offset in a 1KB panel

    // Hoisted QK B-operand: g panels (pre-scaled by LOG2E).
    bf16x8 bg_[2][2];
    #pragma unroll
    for (int mt = 0; mt < 2; mt++)
        #pragma unroll
        for (int kk = 0; kk < 2; kk++)
            bg_[mt][kk] = *(const bf16x8*)(gb + (size_t)(mg*2 + mt)*1024 + kk*512 + lane16);

    const floatx16 zero16 = {};
    floatx16 oacc[2][2];                  // [mt][ct]: ch=ct*32+l31, m=mt*32+crow(r,hi)
    #pragma unroll
    for (int mt = 0; mt < 2; mt++)
        #pragma unroll
        for (int ct = 0; ct < 2; ct++) oacc[mt][ct] = zero16;
    float rsum[2] = {0.f, 0.f};           // per-lane partial rowsum for m=mt*32+l31

    #pragma unroll
    for (int i = 0; i < 4; i++) {
        const int nc = half*32 + 8*i + w; // this half's chunk, parity w

        // QK A-operand: f panels (r11 verbatim).
        bf16x8 af[2][2];
        #pragma unroll
        for (int nt = 0; nt < 2; nt++)
            #pragma unroll
            for (int kk = 0; kk < 2; kk++)
                af[nt][kk] = *(const bf16x8*)(fb + (size_t)(nc*2 + nt)*1024 + kk*512 + lane16);

        // PV B-operand: hv panels (r11 verbatim).
        bf16x8 bv[2][4];
        #pragma unroll
        for (int ct = 0; ct < 2; ct++)
            #pragma unroll
            for (int ks = 0; ks < 4; ks++)
                bv[ct][ks] = *(const bf16x8*)(hb + (size_t)nc*4096 + ct*2048 + ks*512 + lane16);

        // ---- QK + exp2 + in-register P build (T12, r6-verified)
        bf16x8 pa[2][4];                  // [mt][ks]: PV A-frags
        #pragma unroll
        for (int mt = 0; mt < 2; mt++) {
            #pragma unroll
            for (int nt = 0; nt < 2; nt++) {
                floatx16 s = __builtin_amdgcn_mfma_f32_32x32x16_bf16(
                    af[nt][0], bg_[mt][0], zero16, 0, 0, 0);
                s = __builtin_amdgcn_mfma_f32_32x32x16_bf16(
                    af[nt][1], bg_[mt][1], s, 0, 0, 0);
                // lane holds S'[m=mt*32+l31][n=nc*64+nt*32+crow(r,hi)], log2 units

                float p[16];
                #pragma unroll
                for (int r = 0; r < 16; r++) p[r] = exp2_f32(s[r]);

                // rowsum: direct f32 adds (r10-verified numerics)
                #pragma unroll
                for (int r = 0; r < 16; r++) rsum[mt] += p[r];

                unsigned W[8];
                #pragma unroll
                for (int g = 0; g < 8; g++) W[g] = cvt_pk_bf16(p[2*g], p[2*g+1]);

                uintx2 s02 = __builtin_amdgcn_permlane32_swap(W[0], W[2], false, false);
                uintx2 s13 = __builtin_amdgcn_permlane32_swap(W[1], W[3], false, false);
                uintx2 s46 = __builtin_amdgcn_permlane32_swap(W[4], W[6], false, false);
                uintx2 s57 = __builtin_amdgcn_permlane32_swap(W[5], W[7], false, false);

                uintx4 w0 = {s02.x, s13.x, s02.y, s13.y};   // n_local 0..15
                uintx4 w1 = {s46.x, s57.x, s46.y, s57.y};   // n_local 16..31
                pa[mt][nt*2 + 0] = __builtin_bit_cast(bf16x8, w0);
                pa[mt][nt*2 + 1] = __builtin_bit_cast(bf16x8, w1);
            }
        }

        // ---- PV: O[m][ch] += sum_n P[m][n] hv[ch][n]
        #pragma unroll
        for (int mt = 0; mt < 2; mt++)
            #pragma unroll
            for (int ct = 0; ct < 2; ct++)
                #pragma unroll
                for (int ks = 0; ks < 4; ks++)
                    oacc[mt][ct] = __builtin_amdgcn_mfma_f32_32x32x16_bf16(
                        pa[mt][ks], bv[ct][ks], oacc[mt][ct], 0, 0, 0);
    }

    // combine the two lane-halves' complementary n-sets
    #pragma unroll
    for (int mt = 0; mt < 2; mt++)
        rsum[mt] += __shfl_xor(rsum[mt], 32, 64);

    // ---- partial buffers: [pair][half] {O[ch 64][m 64], L[64]}
    const size_t PSTR = 64*64 + 64;
    float* myO = pbuf + ((size_t)pair*2 + half) * PSTR;
    float* myL = myO + 64*64;
    const float* otO = pbuf + ((size_t)pair*2 + (half^1)) * PSTR;
    const float* otL = otO + 64*64;

    // ---- two-pass in-block merge (32 rows per pass through osum)
    #pragma unroll
    for (int mt = 0; mt < 2; mt++) {
        if (mt) __syncthreads();          // pass-0 reads done before reuse
        #pragma unroll
        for (int ct = 0; ct < 2; ct++)
            #pragma unroll
            for (int r = 0; r < 16; r++)
                osum[w][(r&3) + 8*(r>>2) + 4*hi][ct*32 + l31] = oacc[mt][ct][r];
        if (hi == 0)
            lsum[w*64 + mt*32 + l31] = rsum[mt];
        __syncthreads();
        // reduce 8 slots over 32 rows x 64 ch = 2048 cells, 4 per thread
        #pragma unroll
        for (int it = 0; it < 4; it++) {
            const int idx = it*512 + t;
            const int mr = idx & 31;
            const int ch = idx >> 5;
            float a = 0.f;
            #pragma unroll
            for (int s = 0; s < 8; s++) a += osum[s][mr][ch];
            myO[ch*64 + mt*32 + mr] = a;
        }
    }
    if (t < 64) {
        float a = 0.f;
        #pragma unroll
        for (int s = 0; s < 8; s++) a += lsum[s*64 + t];
        myL[t] = a;
    }
    __syncthreads();
    __threadfence();                      // publish partials (r16-validated)
    if (t == 0) sflag = (int)(atomicAdd(&pair_cnt[pair], 1u) & 1u);
    __syncthreads();
    if (sflag == 0) return;               // first arrival: partner finishes
    __threadfence();                      // acquire partner's partials

    // ---- second arrival: merge halves + fused epilogue (64 m x 64 ch)
    if (t < 64) lsum[t] = 1.f / (myL[t] + otL[t]);
    __syncthreads();
    const float gam = gamma_p[0];
    #pragma unroll
    for (int it = 0; it < 8; it++) {
        const int idx = it*512 + t;
        const int m  = idx & 63;          // coalesced in m
        const int ch = idx >> 6;
        float O = myO[ch*64 + m] + otO[ch*64 + m];
        size_t gi = ((size_t)b * CHN + ch) * NN + m0 + m;
        out[gi] = gam * scrub(O * lsum[m]) + x[gi];
    }
}

// ---------------------------------------------------------------------------
extern "C" void kernel_launch(void* const* d_in, const int* in_sizes, int n_in,
                              void* d_out, int out_size, void* d_ws, size_t ws_size,
                              hipStream_t stream)
{
    const float* x     = (const float*)d_in[0];
    const float* y     = (const float*)d_in[1];
    const float* Wf    = (const float*)d_in[2];
    const float* bf    = (const float*)d_in[3];
    const float* Wg    = (const float*)d_in[4];
    const float* bg    = (const float*)d_in[5];
    const float* Wh    = (const float*)d_in[6];
    const float* bh    = (const float*)d_in[7];
    const float* gamma = (const float*)d_in[8];
    float* out = (float*)d_out;

    __bf16* wsb = (__bf16*)d_ws;
    __bf16* fT  = wsb;                                // [4][swizzled 4096x32] = 1 MB
    __bf16* gT  = fT + (size_t)BB * NN * CF;          // 1 MB
    __bf16* hvb = gT + (size_t)BB * NN * CF;          // [4][swizzled 64x4096] = 2 MB
    float* pbuf = (float*)(hvb + (size_t)BB * CHN * NN);  // pair partials, 8.5 MB

    prep_kernel<<<dim3(BB * 128), dim3(256), 0, stream>>>(
        x, y, Wf, bf, Wg, bg, Wh, bh, fT, gT, hvb);
    attn_kernel<<<dim3(BB * 128), dim3(512), 0, stream>>>(
        fT, gT, hvb, pbuf, x, gamma, out);
}

// Round 19
// 92.708 us; speedup vs baseline: 3.6516x; 3.6516x over previous
//
#include <hip/hip_runtime.h>
#include <hip/hip_bf16.h>

// Problem constants (fixed by reference)
#define BB  4
#define CC  64      // input channels
#define NN  4096    // W*H
#define CF  32      // f/g channels (CH/2)
#define CHN 64      // h channels

#define LOG2E 1.4426950408889634f

typedef __attribute__((ext_vector_type(8)))  __bf16 bf16x8;
typedef __attribute__((ext_vector_type(4)))  __bf16 bf16x4;
typedef __attribute__((ext_vector_type(4)))  float  floatx4;
typedef __attribute__((ext_vector_type(16))) float  floatx16;
typedef __attribute__((ext_vector_type(2)))  unsigned int uintx2;
typedef __attribute__((ext_vector_type(4)))  unsigned int uintx4;

__device__ __forceinline__ float scrub(float v) {
    return fminf(fmaxf(v, -1e30f), 1e30f);
}

// v_cvt_pk_bf16_f32 (r6-verified); v_exp_f32 = 2^x (r10-verified).
__device__ __forceinline__ unsigned cvt_pk_bf16(float lo, float hi) {
    unsigned r;
    asm("v_cvt_pk_bf16_f32 %0, %1, %2" : "=v"(r) : "v"(lo), "v"(hi));
    return r;
}
__device__ __forceinline__ float exp2_f32(float x) {
    float r;
    asm("v_exp_f32 %0, %1" : "=v"(r) : "v"(x));
    return r;
}

// ---------------------------------------------------------------------------
// SWIZZLED WORKSPACE LAYOUTS (r11-verified, the -7.7us win). Every attn load
// instruction = one contiguous 1KB panel (lane sub-offset (l31*2+hi)*16B).
//   fT/gT (n,c): (n>>5)*1024 + (c>>4)*512 + (n&31)*16 + ((c>>3)&1)*8 + (c&7)
//   hvb  (ch,n): (n>>6)*4096 + (ch>>5)*2048 + ((n>>4)&3)*512
//                + (ch&31)*16 + ((n>>3)&1)*8 + (n&7)
// ---------------------------------------------------------------------------

// ---------------------------------------------------------------------------
// Kernel 1: 1x1 convs as MFMA GEMM (r11 verbatim: r8 geometry + swizzled
// stores + LOG2E fold on g).
// ---------------------------------------------------------------------------
__global__ __launch_bounds__(256) void prep_kernel(
    const float* __restrict__ x, const float* __restrict__ y,
    const float* __restrict__ Wf, const float* __restrict__ bfp,
    const float* __restrict__ Wg, const float* __restrict__ bgp,
    const float* __restrict__ Wh, const float* __restrict__ bhp,
    __bf16* __restrict__ fT, __bf16* __restrict__ gT, __bf16* __restrict__ hvb)
{
    __shared__ __align__(16) __bf16 wbf[128][72];
    __shared__ float sbias[128];

    const int t  = threadIdx.x;
    const int w  = t >> 6;               // 0..3
    const int l  = t & 63;
    const int lo = l & 15;
    const int q  = l >> 4;

    const int b   = blockIdx.x >> 7;
    const int nb  = blockIdx.x & 127;
    const int nn  = nb * 32 + (w & 1) * 16 + lo;   // 32 nn per block
    const int ctbase = (w < 2) ? 0 : 4;            // ct-half per wave pair

    for (int i = t; i < 128 * CC; i += 256) {
        int row = i >> 6, c = i & 63;
        float wv;
        if (row < 32)      wv = Wf[(size_t)row * CC + c];
        else if (row < 64) wv = Wg[(size_t)(row - 32) * CC + c];
        else               wv = Wh[(size_t)(row - 64) * CC + c];
        wbf[row][c] = (__bf16)wv;
    }
    if (t < 128) {
        if (t < 32)      sbias[t] = bfp[t];
        else if (t < 64) sbias[t] = bgp[t - 32];
        else             sbias[t] = bhp[t - 64];
    }
    __syncthreads();

    const float* xb = x + (size_t)b * CC * NN;
    const float* yb = y + (size_t)b * CC * NN;
    bf16x8 bx[2], by[2];
    #pragma unroll
    for (int kh = 0; kh < 2; kh++)
        #pragma unroll
        for (int j = 0; j < 8; j++) {
            int c = kh * 32 + q * 8 + j;
            by[kh][j] = (__bf16)yb[(size_t)c * NN + nn];
        }
    if (ctbase == 0) {      // bx only needed for ct 0,1
        #pragma unroll
        for (int kh = 0; kh < 2; kh++)
            #pragma unroll
            for (int j = 0; j < 8; j++) {
                int c = kh * 32 + q * 8 + j;
                bx[kh][j] = (__bf16)xb[(size_t)c * NN + nn];
            }
    }

    const floatx4 zero4 = {0.f, 0.f, 0.f, 0.f};
    #pragma unroll
    for (int cti = 0; cti < 4; cti++) {
        const int ct = ctbase + cti;
        const bf16x8* src = (ct < 2) ? bx : by;
        floatx4 acc = zero4;
        #pragma unroll
        for (int kh = 0; kh < 2; kh++) {
            const bf16x8 a = *(const bf16x8*)&wbf[ct*16 + lo][kh*32 + q*8];
            acc = __builtin_amdgcn_mfma_f32_16x16x32_bf16(a, src[kh], acc, 0, 0, 0);
        }
        if (ct < 4) {
            const float sc = (ct < 2) ? 1.0f : LOG2E;   // exp2-fold on g
            bf16x4 pk;
            #pragma unroll
            for (int r = 0; r < 4; r++)
                pk[r] = (__bf16)((acc[r] + sbias[ct*16 + q*4 + r]) * sc);
            __bf16* dstbase = (ct < 2) ? fT : gT;
            const int c0 = (ct & 1) * 16 + q * 4;
            const int off = (nn >> 5)*1024 + (c0 >> 4)*512 + (nn & 31)*16
                          + ((c0 >> 3) & 1)*8 + (c0 & 7);
            *(bf16x4*)&dstbase[(size_t)b * NN * CF + off] = pk;
        } else {
            #pragma unroll
            for (int r = 0; r < 4; r++) {
                int ch = (ct - 4) * 16 + q*4 + r;
                const int off = (nn >> 6)*4096 + (ch >> 5)*2048
                              + ((nn >> 4) & 3)*512 + (ch & 31)*16
                              + ((nn >> 3) & 1)*8 + (nn & 7);
                hvb[(size_t)b * CHN * NN + off] =
                    (__bf16)(acc[r] + sbias[64 + ch]);
            }
        }
    }
}

// ---------------------------------------------------------------------------
// Kernel 2: fused flash attention — EXACT r11/r17 (best verified: 92.8 /
// 96.0us, ±3us harness noise): 32x32 swapped-QK, in-register P via T12,
// zero LDS/fences in loop, swizzled panel loads, exp2-fold, f32 rowsum.
// Grid BB*64, 512 thr, 8 parity waves, 64-row m-tile, 1 block/CU.
// r12-r18: occupancy x4 + rotation + BM=128 all regressed (three were
// allocator-induced spills at HIP source level) — permanently reverted.
// ---------------------------------------------------------------------------
__global__ __launch_bounds__(512, 2) void attn_kernel(
    const __bf16* __restrict__ fT, const __bf16* __restrict__ gT,
    const __bf16* __restrict__ hvb,
    const float* __restrict__ x, const float* __restrict__ gamma_p,
    float* __restrict__ out)
{
    __shared__ float osum[8][64][67];   // 137,216 B
    __shared__ float lsum[512];         //   2,048 B  [w*64 + m]

    const int t   = threadIdx.x;
    const int w   = t >> 6;               // wave = n-parity (0..7)
    const int l   = t & 63;
    const int l31 = l & 31;
    const int hi  = l >> 5;

    // XCD swizzle (r3): XCD pair (2b,2b+1) serves batch b.
    const int slot = blockIdx.x;          // 0..255
    const int xcd  = slot & 7;
    const int b    = xcd >> 1;
    const int mg   = ((xcd & 1) << 5) | (slot >> 3);   // 0..63
    const int m0   = mg * 64;

    const __bf16* fb = fT  + (size_t)b * NN * CF;
    const __bf16* gb = gT  + (size_t)b * NN * CF;
    const __bf16* hb = hvb + (size_t)b * CHN * NN;

    const int lane16 = (l31 * 2 + hi) * 8;   // elem sub-offset in a 1KB panel

    // Hoisted QK B-operand: g panels (pre-scaled by LOG2E).
    bf16x8 bg_[2][2];
    #pragma unroll
    for (int mt = 0; mt < 2; mt++)
        #pragma unroll
        for (int kk = 0; kk < 2; kk++)
            bg_[mt][kk] = *(const bf16x8*)(gb + (size_t)(mg*2 + mt)*1024 + kk*512 + lane16);

    const floatx16 zero16 = {};
    floatx16 oacc[2][2];                  // [mt][ct]: ch=ct*32+l31, m=mt*32+crow(r,hi)
    #pragma unroll
    for (int mt = 0; mt < 2; mt++)
        #pragma unroll
        for (int ct = 0; ct < 2; ct++) oacc[mt][ct] = zero16;
    float rsum[2] = {0.f, 0.f};           // per-lane partial rowsum for m=mt*32+l31

    for (int i = 0; i < 8; i++) {
        const int nc = 8*i + w;           // 64-wide n-chunk index (parity w)

        // QK A-operand: f panels. A-frag: lane -> row n = l31 (+nt*32).
        bf16x8 af[2][2];
        #pragma unroll
        for (int nt = 0; nt < 2; nt++)
            #pragma unroll
            for (int kk = 0; kk < 2; kk++)
                af[nt][kk] = *(const bf16x8*)(fb + (size_t)(nc*2 + nt)*1024 + kk*512 + lane16);

        // PV B-operand: hv panels. lane -> col ch = ct*32+l31, k n = ks*16+hi*8+j.
        bf16x8 bv[2][4];
        #pragma unroll
        for (int ct = 0; ct < 2; ct++)
            #pragma unroll
            for (int ks = 0; ks < 4; ks++)
                bv[ct][ks] = *(const bf16x8*)(hb + (size_t)nc*4096 + ct*2048 + ks*512 + lane16);

        // ---- QK + exp2 + in-register P build (T12, r6-verified)
        bf16x8 pa[2][4];                  // [mt][ks]: PV A-frags
        #pragma unroll
        for (int mt = 0; mt < 2; mt++) {
            #pragma unroll
            for (int nt = 0; nt < 2; nt++) {
                floatx16 s = __builtin_amdgcn_mfma_f32_32x32x16_bf16(
                    af[nt][0], bg_[mt][0], zero16, 0, 0, 0);
                s = __builtin_amdgcn_mfma_f32_32x32x16_bf16(
                    af[nt][1], bg_[mt][1], s, 0, 0, 0);
                // lane holds S'[m=mt*32+l31][n=nc*64+nt*32+crow(r,hi)], log2 units

                float p[16];
                #pragma unroll
                for (int r = 0; r < 16; r++) p[r] = exp2_f32(s[r]);

                // rowsum: direct f32 adds (r10-verified numerics)
                #pragma unroll
                for (int r = 0; r < 16; r++) rsum[mt] += p[r];

                unsigned W[8];
                #pragma unroll
                for (int g = 0; g < 8; g++) W[g] = cvt_pk_bf16(p[2*g], p[2*g+1]);

                uintx2 s02 = __builtin_amdgcn_permlane32_swap(W[0], W[2], false, false);
                uintx2 s13 = __builtin_amdgcn_permlane32_swap(W[1], W[3], false, false);
                uintx2 s46 = __builtin_amdgcn_permlane32_swap(W[4], W[6], false, false);
                uintx2 s57 = __builtin_amdgcn_permlane32_swap(W[5], W[7], false, false);

                uintx4 w0 = {s02.x, s13.x, s02.y, s13.y};   // n_local 0..15
                uintx4 w1 = {s46.x, s57.x, s46.y, s57.y};   // n_local 16..31
                pa[mt][nt*2 + 0] = __builtin_bit_cast(bf16x8, w0);
                pa[mt][nt*2 + 1] = __builtin_bit_cast(bf16x8, w1);
            }
        }

        // ---- PV: O[m][ch] += sum_n P[m][n] hv[ch][n]
        #pragma unroll
        for (int mt = 0; mt < 2; mt++)
            #pragma unroll
            for (int ct = 0; ct < 2; ct++)
                #pragma unroll
                for (int ks = 0; ks < 4; ks++)
                    oacc[mt][ct] = __builtin_amdgcn_mfma_f32_32x32x16_bf16(
                        pa[mt][ks], bv[ct][ks], oacc[mt][ct], 0, 0, 0);
    }

    // combine the two lane-halves' complementary n-sets
    #pragma unroll
    for (int mt = 0; mt < 2; mt++)
        rsum[mt] += __shfl_xor(rsum[mt], 32, 64);

    // ---- parallel merge across the 8 parity waves (r2 pattern)
    #pragma unroll
    for (int mt = 0; mt < 2; mt++) {
        #pragma unroll
        for (int ct = 0; ct < 2; ct++)
            #pragma unroll
            for (int r = 0; r < 16; r++)
                osum[w][mt*32 + ((r&3) + 8*(r>>2) + 4*hi)][ct*32 + l31] =
                    oacc[mt][ct][r];
        if (hi == 0)
            lsum[w*64 + mt*32 + l31] = rsum[mt];
    }
    __syncthreads();

    // ---- 8-slot reduce + fused epilogue: out = gamma * osum/lsum + x
    const float gam = gamma_p[0];
    const int m  = t & 63;          // coalesced across lanes (full wave = 64 m)
    const int cb = t >> 6;          // 0..7
    float lt = 0.f;
    #pragma unroll
    for (int s = 0; s < 8; s++) lt += lsum[s*64 + m];
    const float inv = 1.f / lt;
    #pragma unroll
    for (int it = 0; it < 8; it++) {
        const int ch = it*8 + cb;
        float acc = 0.f;
        #pragma unroll
        for (int s = 0; s < 8; s++) acc += osum[s][m][ch];
        size_t gi = ((size_t)b * CHN + ch) * NN + m0 + m;
        float ov = scrub(acc * inv);
        out[gi] = gam * ov + x[gi];
    }
}

// ---------------------------------------------------------------------------
extern "C" void kernel_launch(void* const* d_in, const int* in_sizes, int n_in,
                              void* d_out, int out_size, void* d_ws, size_t ws_size,
                              hipStream_t stream)
{
    const float* x     = (const float*)d_in[0];
    const float* y     = (const float*)d_in[1];
    const float* Wf    = (const float*)d_in[2];
    const float* bf    = (const float*)d_in[3];
    const float* Wg    = (const float*)d_in[4];
    const float* bg    = (const float*)d_in[5];
    const float* Wh    = (const float*)d_in[6];
    const float* bh    = (const float*)d_in[7];
    const float* gamma = (const float*)d_in[8];
    float* out = (float*)d_out;

    __bf16* wsb = (__bf16*)d_ws;
    __bf16* fT  = wsb;                                // [4][swizzled 4096x32] = 1 MB
    __bf16* gT  = fT + (size_t)BB * NN * CF;          // 1 MB
    __bf16* hvb = gT + (size_t)BB * NN * CF;          // [4][swizzled 64x4096] = 2 MB
    // total 4 MB of ws

    prep_kernel<<<dim3(BB * 128), dim3(256), 0, stream>>>(
        x, y, Wf, bf, Wg, bg, Wh, bh, fT, gT, hvb);
    attn_kernel<<<dim3(BB * 64), dim3(512), 0, stream>>>(
        fT, gT, hvb, x, gamma, out);
}